// Round 1
// baseline (98.089 us; speedup 1.0000x reference)
//
#include <hip/hip_runtime.h>
#include <hip/hip_bf16.h>
#include <math.h>

#define BB 2
#define FF 32
#define NN 1024
#define HH 64
#define TI 8   // i-rows per block in edge kernel

// ---------------------------------------------------------------------------
// Kernel 1: hi[b,n,h] = sum_f emb[b,f,n] * W1[h,f]
//           hjb[b,n,h] = sum_f emb[b,f,n] * W1[h,F+f] + b1[h]
// One thread per (b,n,h); h fastest for coalesced writes.
// ---------------------------------------------------------------------------
__global__ __launch_bounds__(256) void prep_kernel(
    const float* __restrict__ emb,   // (B,F,N)
    const float* __restrict__ W1,    // (H, 2F)
    const float* __restrict__ b1,    // (H)
    float* __restrict__ hi,          // (B,N,H)
    float* __restrict__ hjb)         // (B,N,H)
{
    int t = blockIdx.x * 256 + threadIdx.x;   // t in [0, B*N*H)
    int h = t & (HH - 1);
    int n = (t >> 6) & (NN - 1);
    int b = t >> 16;                          // 6 + 10 bits

    const float* e = emb + (size_t)b * FF * NN + n;  // stride NN over f
    const float* w = W1 + (size_t)h * (2 * FF);

    float si = 0.f, sj = 0.f;
#pragma unroll
    for (int f = 0; f < FF; ++f) {
        float ev = e[(size_t)f * NN];
        si = fmaf(ev, w[f], si);
        sj = fmaf(ev, w[FF + f], sj);
    }
    hi[t]  = si;
    hjb[t] = sj + b1[h];
}

// ---------------------------------------------------------------------------
// Kernel 2: out[b,i,j] = sigmoid( sum_h relu(hi[b,i,h]+hjb[b,j,h])*W2[h] + b2 )
// Thread owns one j (hjb row cached in 64 VGPRs), loops TI values of i.
// hi/W2 accesses are wave-uniform -> scalar loads.
// ---------------------------------------------------------------------------
__global__ __launch_bounds__(256) void edge_kernel(
    const float* __restrict__ hi,    // (B,N,H)
    const float* __restrict__ hjb,   // (B,N,H)
    const float* __restrict__ W2,    // (H)
    const float* __restrict__ b2,    // (1)
    float* __restrict__ out)         // (B,N,N)
{
    const int j  = blockIdx.x * 256 + threadIdx.x;
    const int i0 = blockIdx.y * TI;
    const int b  = blockIdx.z;

    // load this thread's hjb row (64 floats) into registers
    float4 hjr[16];
    const float4* hjp = (const float4*)(hjb + ((size_t)b * NN + j) * HH);
#pragma unroll
    for (int k = 0; k < 16; ++k) hjr[k] = hjp[k];

    const float b2v = b2[0];
    const float* hib = hi + ((size_t)b * NN + i0) * HH;
    float* op = out + ((size_t)b * NN + i0) * NN + j;

#pragma unroll
    for (int ii = 0; ii < TI; ++ii) {
        const float* hirow = hib + ii * HH;   // wave-uniform address
        float a0 = 0.f, a1 = 0.f, a2 = 0.f, a3 = 0.f;
#pragma unroll
        for (int k = 0; k < 16; ++k) {
            const float4 hj4 = hjr[k];
            float h0 = fmaxf(hj4.x + hirow[4 * k + 0], 0.f);
            float h1 = fmaxf(hj4.y + hirow[4 * k + 1], 0.f);
            float h2 = fmaxf(hj4.z + hirow[4 * k + 2], 0.f);
            float h3 = fmaxf(hj4.w + hirow[4 * k + 3], 0.f);
            a0 = fmaf(h0, W2[4 * k + 0], a0);
            a1 = fmaf(h1, W2[4 * k + 1], a1);
            a2 = fmaf(h2, W2[4 * k + 2], a2);
            a3 = fmaf(h3, W2[4 * k + 3], a3);
        }
        float s = (a0 + a1) + (a2 + a3) + b2v;
        op[(size_t)ii * NN] = 1.0f / (1.0f + __expf(-s));
    }
}

// ---------------------------------------------------------------------------
extern "C" void kernel_launch(void* const* d_in, const int* in_sizes, int n_in,
                              void* d_out, int out_size, void* d_ws, size_t ws_size,
                              hipStream_t stream) {
    // inputs: 0 adj_in (unused), 1 emb_in, 2 layer (unused), 3 W1, 4 b1, 5 W2, 6 b2
    const float* emb = (const float*)d_in[1];
    const float* W1  = (const float*)d_in[3];
    const float* b1  = (const float*)d_in[4];
    const float* W2  = (const float*)d_in[5];
    const float* b2  = (const float*)d_in[6];
    float* out = (float*)d_out;

    float* hi  = (float*)d_ws;                        // B*N*H floats
    float* hjb = hi + (size_t)BB * NN * HH;           // B*N*H floats

    prep_kernel<<<(BB * NN * HH) / 256, 256, 0, stream>>>(emb, W1, b1, hi, hjb);

    dim3 grid(NN / 256, NN / TI, BB);
    edge_kernel<<<grid, 256, 0, stream>>>(hi, hjb, W2, b2, out);
}